// Round 1
// baseline (95.019 us; speedup 1.0000x reference)
//
#include <hip/hip_runtime.h>

// Problem constants (B=2, T=2048, D=1024, N_EXP=8, TOP_K=2, CAP_FACTOR=1.25)
#define N_TOK   4096          // B*T
#define DDIM    1024
#define N_EXP   8
#define CAP     1280          // floor(2*1.25*4096/8) = 1280 (even, >= 4)
#define CB_ELEMS (N_TOK * N_EXP * CAP)   // 41,943,040 floats per output tensor

// ws layout:
//   [0,      16384) : int   e0[4096]   expert id, slot k=0 (argmax)
//   [16384,  32768) : int   e1[4096]   expert id, slot k=1 (2nd max)
//   [32768,  98304) : int4  rec[4096]  {er0=(e0<<16|r0), w0bits, er1=(e1<<16|r1), w1bits}

// ---------------------------------------------------------------------------
// Kernel 1: router — logits (4096x8 GEMV), top-2, softmax over top-2.
// One wave per token; lanes split D=1024 as float4 chunks.
// ---------------------------------------------------------------------------
__global__ __launch_bounds__(256) void router_kernel(
    const float* __restrict__ x, const float* __restrict__ wg,
    int* __restrict__ e0, int* __restrict__ e1, int4* __restrict__ rec)
{
    const int wave = threadIdx.x >> 6;      // 0..3
    const int lane = threadIdx.x & 63;
    const int t = blockIdx.x * 4 + wave;
    if (t >= N_TOK) return;

    const float4* xt  = (const float4*)(x + (size_t)t * DDIM);   // 256 float4
    const float4* wg4 = (const float4*)wg;                        // [8][256]

    float acc[N_EXP];
#pragma unroll
    for (int e = 0; e < N_EXP; ++e) acc[e] = 0.f;

#pragma unroll
    for (int it = 0; it < 4; ++it) {        // 256/64 = 4 chunks
        const int d4 = lane + it * 64;
        const float4 xv = xt[d4];
#pragma unroll
        for (int e = 0; e < N_EXP; ++e) {
            const float4 wv = wg4[e * 256 + d4];
            acc[e] = fmaf(xv.x, wv.x,
                     fmaf(xv.y, wv.y,
                     fmaf(xv.z, wv.z,
                     fmaf(xv.w, wv.w, acc[e]))));
        }
    }

    // full-wave reduction per expert
#pragma unroll
    for (int e = 0; e < N_EXP; ++e) {
#pragma unroll
        for (int off = 32; off >= 1; off >>= 1)
            acc[e] += __shfl_xor(acc[e], off, 64);
    }

    if (lane == 0) {
        // stable top-2 (strict >) matches jax.lax.top_k tie-breaking
        float v0 = -3.402823466e38f, v1 = -3.402823466e38f;
        int   i0 = 0, i1 = 0;
#pragma unroll
        for (int e = 0; e < N_EXP; ++e) {
            const float v = acc[e];
            if (v > v0)      { v1 = v0; i1 = i0; v0 = v; i0 = e; }
            else if (v > v1) { v1 = v;  i1 = e; }
        }
        const float ex = expf(v1 - v0);
        const float inv = 1.f / (1.f + ex);
        const float p0 = inv;          // softmax([v0,v1])[0]
        const float p1 = ex * inv;     // softmax([v0,v1])[1]

        e0[t] = i0;
        e1[t] = i1;
        int4 r;
        r.x = i0 << 16;                // rank OR'd in by scan kernel
        r.y = __float_as_int(p0);
        r.z = i1 << 16;
        r.w = __float_as_int(p1);
        rec[t] = r;
    }
}

// ---------------------------------------------------------------------------
// Kernel 2: ordered rank scan. Entry order = [k=0: tok 0..4095][k=1: tok 0..4095]
// (matches the reference cumsum over the k-major flattened mask).
// One wave per expert (8 waves); ballot-prefix gives exact sequential ranks.
// ---------------------------------------------------------------------------
__global__ __launch_bounds__(512) void scan_kernel(
    const int* __restrict__ e0, const int* __restrict__ e1,
    int4* __restrict__ rec, float* __restrict__ out_used)
{
    __shared__ int lds_e[2 * N_TOK];   // 32 KB
    for (int i = threadIdx.x; i < N_TOK; i += 512) lds_e[i]          = e0[i];
    for (int i = threadIdx.x; i < N_TOK; i += 512) lds_e[N_TOK + i]  = e1[i];
    __syncthreads();

    const int expert = threadIdx.x >> 6;   // wave id == expert id
    const int lane   = threadIdx.x & 63;
    const unsigned long long lt_mask = (lane == 63) ? 0x7FFFFFFFFFFFFFFFull
                                                    : ((1ull << lane) - 1ull);
    int base = 0;
    for (int it = 0; it < (2 * N_TOK) / 64; ++it) {
        const int i = it * 64 + lane;
        const int e = lds_e[i];
        const bool match = (e == expert);
        const unsigned long long bal = __ballot(match);
        if (match) {
            const int r  = base + __popcll(bal & lt_mask);
            const int er = (expert << 16) | r;   // r<1280 kept; r>=cap never matches c
            if (i < N_TOK) rec[i].x = er;
            else           rec[i - N_TOK].z = er;
        }
        base += __popcll(bal);
    }
    if (lane == 0) out_used[expert] = (float)min(base, CAP);
}

// ---------------------------------------------------------------------------
// Kernel 3: fill cb_weight + sec_mask (the 335 MB store pass).
// Pure gather: each float4 position compares its (e<<16|c) key against the
// token's two packed assignments. rec[t] is 16B/token -> L1/L2 resident.
// ---------------------------------------------------------------------------
__global__ __launch_bounds__(256) void fill_kernel(
    const int4* __restrict__ rec,
    float4* __restrict__ cb, float4* __restrict__ mask)
{
    const int total4 = CB_ELEMS / 4;   // 10,485,760
    const int stride = gridDim.x * blockDim.x;
    for (int i = blockIdx.x * blockDim.x + threadIdx.x; i < total4; i += stride) {
        const int base = i << 2;                     // element index, < 2^26
        const int t  = base / (N_EXP * CAP);         // /10240 (magic mul)
        const int o  = base - t * (N_EXP * CAP);
        const int e  = o / CAP;                      // /1280
        const int c0 = o - e * CAP;
        const int4 r = rec[t];
        const int key = (e << 16) | c0;
        const float w0 = __int_as_float(r.y);
        const float w1 = __int_as_float(r.w);

        float4 v;
        v.x = (r.x == key    ) ? w0 : (r.z == key    ) ? w1 : 0.f;
        v.y = (r.x == key + 1) ? w0 : (r.z == key + 1) ? w1 : 0.f;
        v.z = (r.x == key + 2) ? w0 : (r.z == key + 2) ? w1 : 0.f;
        v.w = (r.x == key + 3) ? w0 : (r.z == key + 3) ? w1 : 0.f;
        cb[i] = v;

        float4 m;
        m.x = (v.x != 0.f) ? 1.f : 0.f;
        m.y = (v.y != 0.f) ? 1.f : 0.f;
        m.z = (v.z != 0.f) ? 1.f : 0.f;
        m.w = (v.w != 0.f) ? 1.f : 0.f;
        mask[i] = m;
    }
}

// ---------------------------------------------------------------------------
extern "C" void kernel_launch(void* const* d_in, const int* in_sizes, int n_in,
                              void* d_out, int out_size, void* d_ws, size_t ws_size,
                              hipStream_t stream)
{
    const float* x  = (const float*)d_in[0];   // [2,2048,1024] f32
    const float* wg = (const float*)d_in[1];   // [8,1024] f32
    float* out = (float*)d_out;                // [8] used_cap | [41.94M] cb | [41.94M] mask

    char* ws = (char*)d_ws;
    int*  e0  = (int*)(ws);
    int*  e1  = (int*)(ws + 16384);
    int4* rec = (int4*)(ws + 32768);

    router_kernel<<<N_TOK / 4, 256, 0, stream>>>(x, wg, e0, e1, rec);
    scan_kernel<<<1, 512, 0, stream>>>(e0, e1, rec, out);

    float4* cb   = (float4*)(out + 8);
    float4* mask = (float4*)(out + 8 + (size_t)CB_ELEMS);
    fill_kernel<<<2048, 256, 0, stream>>>(rec, cb, mask);
}